// Round 5
// baseline (435.021 us; speedup 1.0000x reference)
//
#include <hip/hip_runtime.h>
#include <cstdint>
#include <cstddef>

// Problem: B=32, C=768, H=W=32 (HW=1024).
// out[b,c,hw] = (0.5 + 0.5 * cos_gate(b,c)) * X[b,c,hw]
// cos_gate = dot(K_c,V_c)/((||K_c||+1e-12)(||V_c||+1e-12)),
// K = Wk @ Xn, V = Wv @ Xn, Xn = X * rsqrt(mean_c X^2 + 1e-6).
//
// r5: B-resident GEMM. Block = one (b, 64-hw) slice; B[12][64][64] = 96 KB LDS
// staged ONCE (kills the 6x B amplification that pinned r0-r4 at ~2.6 TB/s of
// L3-side supply). A = Wst streams via 2x32 KB LDS dbuf from the per-XCD
// L2-resident 2.25 MB Wst (every block reads it -> L2 hits, 1-phase lead
// suffices). One barrier per phase. LDS = 160 KB exactly.

#define B_   32
#define C_   768
#define HW_  1024
#define CHW_ (C_ * HW_)          // 786432
#define EPS_NORM 1e-6f
#define EPS_COS  1e-12f

using f32x4  = __attribute__((ext_vector_type(4))) float;
using bf16x8 = __attribute__((ext_vector_type(8))) short;   // 8 bf16 = 4 VGPRs

__device__ inline unsigned short f2bf(float f) {
    union { float f; unsigned u; } v; v.f = f;
    unsigned u = v.u;
    u += 0x7fffu + ((u >> 16) & 1u);        // round-to-nearest-even
    return (unsigned short)(u >> 16);
}

// async global->LDS, 16 B per lane. LDS dst is wave-uniform base + lane*16;
// global src is per-lane (pre-swizzled chunk^(row&7) source pattern).
__device__ __forceinline__ void load16_lds(const unsigned short* g, short* l) {
    __builtin_amdgcn_global_load_lds(
        (const __attribute__((address_space(1))) unsigned int*)g,
        (__attribute__((address_space(3))) unsigned int*)l,
        16, 0, 0);
}

#define WAITVM(n) asm volatile("s_waitcnt vmcnt(" #n ")" ::: "memory")
#define SB0 __builtin_amdgcn_sched_barrier(0)

// ---------------------------------------------------------------------------
// K1: cast + row-interleave first 1536 rows of W_in (fp32) -> bf16, plus
// wsA zeroing (blocks 0..95), replacing the hipMemsetAsync dispatch.
// Wst[2c+s] = W[s*768 + c]. grid 1536 blocks x 192 threads (1 float4/thread).
// ---------------------------------------------------------------------------
__global__ void wconv_kernel(const float* __restrict__ W, unsigned short* __restrict__ Wst,
                             float* __restrict__ wsA) {
    const int orow = blockIdx.x;               // 0..1535
    const int c4   = threadIdx.x;              // 0..191
    if (orow < 96) {                           // zero wsA: 96*192 float4 = 294912 B
        const float4 z = {0.f, 0.f, 0.f, 0.f};
        reinterpret_cast<float4*>(wsA)[orow * 192 + c4] = z;
    }
    const int irow = (orow & 1) * 768 + (orow >> 1);
    const float4 v = reinterpret_cast<const float4*>(W + (size_t)irow * 768)[c4];
    ushort4 o;
    o.x = f2bf(v.x); o.y = f2bf(v.y); o.z = f2bf(v.z); o.w = f2bf(v.w);
    reinterpret_cast<ushort4*>(Wst + (size_t)orow * 768)[c4] = o;
}

// ---------------------------------------------------------------------------
// K2 (fused sumsq + normalize + transpose): unchanged from r3 (proven).
// ---------------------------------------------------------------------------
__global__ __launch_bounds__(256) void norm_kernel(const float* __restrict__ X,
                                                   unsigned short* __restrict__ Xnt) {
    const int b   = blockIdx.y;
    const int hw0 = blockIdx.x * 64;
    const int tid = threadIdx.x;
    __shared__ float4 P[256];          // partials, then per-hw-quad scales in P[0..15]
    __shared__ short  T[64][78];       // transpose tile (pad 78: ~2-way, free)

    const int cg = tid >> 4;           // c group 0..15
    const int q4 = tid & 15;           // hw quad 0..15
    const float* xb = X + (size_t)b * CHW_ + hw0 + q4 * 4;
    float4 s = {0.f, 0.f, 0.f, 0.f};
    #pragma unroll 4
    for (int c = cg; c < 768; c += 16) {
        float4 v = *reinterpret_cast<const float4*>(xb + (size_t)c * HW_);
        s.x += v.x * v.x; s.y += v.y * v.y; s.z += v.z * v.z; s.w += v.w * v.w;
    }
    P[tid] = s;
    __syncthreads();
    if (tid < 16) {
        float4 a = P[tid];
        #pragma unroll
        for (int g = 1; g < 16; ++g) {
            float4 v = P[g * 16 + tid];
            a.x += v.x; a.y += v.y; a.z += v.z; a.w += v.w;
        }
        float4 sc;
        sc.x = rsqrtf(a.x * (1.f / 768.f) + EPS_NORM);
        sc.y = rsqrtf(a.y * (1.f / 768.f) + EPS_NORM);
        sc.z = rsqrtf(a.z * (1.f / 768.f) + EPS_NORM);
        sc.w = rsqrtf(a.w * (1.f / 768.f) + EPS_NORM);
        P[tid] = sc;
    }
    __syncthreads();

    #pragma unroll 1
    for (int ch = 0; ch < 12; ++ch) {
        const int c0 = ch * 64;
        #pragma unroll
        for (int it = 0; it < 4; ++it) {
            int q  = it * 256 + tid;    // 0..1023
            int r  = q >> 4;            // c row in tile
            int c4 = (q & 15) * 4;      // hw col in tile
            const float4 x = *reinterpret_cast<const float4*>(
                X + (size_t)b * CHW_ + (size_t)(c0 + r) * HW_ + hw0 + c4);
            const float4 sc = P[q & 15];
            ushort4 o;
            o.x = f2bf(x.x * sc.x); o.y = f2bf(x.y * sc.y);
            o.z = f2bf(x.z * sc.z); o.w = f2bf(x.w * sc.w);
            *reinterpret_cast<ushort4*>(&T[r][c4]) = o;
        }
        __syncthreads();
        #pragma unroll
        for (int it = 0; it < 2; ++it) {
            int q  = it * 256 + tid;    // 0..511
            int rp = q >> 3;            // hw row
            int cc = (q & 7) * 8;       // c chunk
            __align__(16) unsigned short tmp[8];
            #pragma unroll
            for (int j = 0; j < 8; ++j) tmp[j] = (unsigned short)T[cc + j][rp];
            *reinterpret_cast<uint4*>(
                Xnt + (size_t)b * CHW_ + (size_t)(hw0 + rp) * C_ + c0 + cc) =
                *reinterpret_cast<const uint4*>(tmp);
        }
        __syncthreads();
    }
}

// ---------------------------------------------------------------------------
// K4: B-resident 1536x64 GEMM + fused reductions.
// 512 blocks (16 hw x 32 b) x 512 thr = 8 waves (4M x 2N). Wave tile 64x32.
// LDS: sB[12][64][64] (96 KB, staged once) + sA[2][256][64] (64 KB dbuf).
// Phase (ct,kt): ONE barrier. Skeleton:
//   [vmcnt(0) unless after dump]  -- my 4 tile-(ct,kt) stage loads done
//   s_barrier                     -- tile valid chip-wide; ALSO: every wave
//                                    finished last phase's reads (its lgkm0
//                                    preceded its arrival), so the buffer this
//                                    phase stages into is free.
//   ds_read A-frags(buf kt&1) + B-frags(sB[kt]); issue 4 stage loads for the
//   next tile -> buf (kt+1)&1; lgkmcnt(0); 16 MFMA.
// Per-ct dump: exactly 24 atomics/wave then vmcnt(24) => the 4 stage loads
// (older than the atomics, in-order retirement) are drained; the kt==0 phase
// after a dump therefore skips its vmcnt guard.
// Tail (ct5,kt11) stages tile (5,10) again: same buffer parity, identical
// bytes => race-free dead stage.
// ---------------------------------------------------------------------------
template<int KT, bool GUARD>
__device__ __forceinline__ void phase(const short* ArA, const short* BrA,
        short* st0, short* st1, const unsigned short* srcA,
        int slot0, int slot1, f32x4 (&acc)[4][2]) {
    if constexpr (GUARD) { WAITVM(0); }
    SB0;
    __builtin_amdgcn_s_barrier();
    SB0;
    bf16x8 a0[4], a1[4], b0[2], b1[2];
    const short* Ab = ArA + ((KT & 1) << 14);
    const short* Bb = BrA + (KT << 12);
    #pragma unroll
    for (int n = 0; n < 2; ++n) {
        b0[n] = *reinterpret_cast<const bf16x8*>(Bb + (n << 10) + slot0);
        b1[n] = *reinterpret_cast<const bf16x8*>(Bb + (n << 10) + slot1);
    }
    #pragma unroll
    for (int i = 0; i < 4; ++i) {
        a0[i] = *reinterpret_cast<const bf16x8*>(Ab + (i << 10) + slot0);
        a1[i] = *reinterpret_cast<const bf16x8*>(Ab + (i << 10) + slot1);
    }
    short* st = ((KT + 1) & 1) ? st1 : st0;            // compile-time select
    #pragma unroll
    for (int j = 0; j < 4; ++j)
        load16_lds(srcA + j * 49152, st + (j << 12));  // 4 x 64 rows
    asm volatile("s_waitcnt lgkmcnt(0)" ::: "memory");
    SB0;
    __builtin_amdgcn_s_setprio(1);
    #pragma unroll
    for (int i = 0; i < 4; ++i)
        #pragma unroll
        for (int n = 0; n < 2; ++n) {
            acc[i][n] = __builtin_amdgcn_mfma_f32_16x16x32_bf16(a0[i], b0[n], acc[i][n], 0, 0, 0);
            acc[i][n] = __builtin_amdgcn_mfma_f32_16x16x32_bf16(a1[i], b1[n], acc[i][n], 0, 0, 0);
        }
    __builtin_amdgcn_s_setprio(0);
    SB0;
}

__device__ __forceinline__ void dump_acc(f32x4 (&acc)[4][2], float* __restrict__ wsAb,
                                         int ct, int wm, int quad, int l15) {
    #pragma unroll
    for (int i = 0; i < 4; ++i) {
        float d0, e0, f0, d1, e1, f1;
        {
            f32x4 x = acc[i][0], y = acc[i][1];
            d0 = x[0]*x[1] + y[0]*y[1]; e0 = x[0]*x[0] + y[0]*y[0]; f0 = x[1]*x[1] + y[1]*y[1];
            d1 = x[2]*x[3] + y[2]*y[3]; e1 = x[2]*x[2] + y[2]*y[2]; f1 = x[3]*x[3] + y[3]*y[3];
            acc[i][0] = (f32x4){0.f,0.f,0.f,0.f};
            acc[i][1] = (f32x4){0.f,0.f,0.f,0.f};
        }
        #pragma unroll
        for (int off = 1; off < 16; off <<= 1) {     // 16-lane (hw) reduce
            d0 += __shfl_xor(d0, off); e0 += __shfl_xor(e0, off); f0 += __shfl_xor(f0, off);
            d1 += __shfl_xor(d1, off); e1 += __shfl_xor(e1, off); f1 += __shfl_xor(f1, off);
        }
        if (l15 == 0) {                              // 24 atomic instrs per wave
            const int ch = ct * 128 + ((wm + 16 * i + 4 * quad) >> 1);
            float* dst = wsAb + (size_t)ch * 3;
            atomicAdd(dst + 0, d0); atomicAdd(dst + 1, e0); atomicAdd(dst + 2, f0);
            atomicAdd(dst + 3, d1); atomicAdd(dst + 4, e1); atomicAdd(dst + 5, f1);
        }
    }
    WAITVM(24);    // drain the 4 (older) stage loads; atomics may stay in flight
    SB0;
}

template<bool G0>
__device__ __forceinline__ void ct_body(const short* ArA, const short* BrA,
        short* st0, short* st1, const unsigned short* Acur,
        int slot0, int slot1, f32x4 (&acc)[4][2]) {
    phase< 0, G0  >(ArA, BrA, st0, st1, Acur +  1 * 64, slot0, slot1, acc);
    phase< 1, true>(ArA, BrA, st0, st1, Acur +  2 * 64, slot0, slot1, acc);
    phase< 2, true>(ArA, BrA, st0, st1, Acur +  3 * 64, slot0, slot1, acc);
    phase< 3, true>(ArA, BrA, st0, st1, Acur +  4 * 64, slot0, slot1, acc);
    phase< 4, true>(ArA, BrA, st0, st1, Acur +  5 * 64, slot0, slot1, acc);
    phase< 5, true>(ArA, BrA, st0, st1, Acur +  6 * 64, slot0, slot1, acc);
    phase< 6, true>(ArA, BrA, st0, st1, Acur +  7 * 64, slot0, slot1, acc);
    phase< 7, true>(ArA, BrA, st0, st1, Acur +  8 * 64, slot0, slot1, acc);
    phase< 8, true>(ArA, BrA, st0, st1, Acur +  9 * 64, slot0, slot1, acc);
    phase< 9, true>(ArA, BrA, st0, st1, Acur + 10 * 64, slot0, slot1, acc);
    phase<10, true>(ArA, BrA, st0, st1, Acur + 11 * 64, slot0, slot1, acc);
    phase<11, true>(ArA, BrA, st0, st1, Acur + 196608,  slot0, slot1, acc);  // next ct, kt0
}

__global__ __launch_bounds__(512, 1) void gemm_kernel(
        const unsigned short* __restrict__ Wst,   // [1536][768] bf16, interleaved K/V
        const unsigned short* __restrict__ Xnt,   // [B][HW][C] bf16
        float* __restrict__ wsA) {
    const int hw0 = blockIdx.x << 6;
    const int b   = blockIdx.y;
    const int tid  = threadIdx.x;
    const int lane = tid & 63;
    const int wave = tid >> 6;
    const int l15  = lane & 15;
    const int quad = lane >> 4;
    const int lb7  = l15 & 7;
    const int wm   = (wave >> 1) << 6;            // M rows 0/64/128/192
    const int wn   = (wave & 1) << 5;             // hw cols 0/32
    const int slot0 = (quad ^ lb7) << 3;          // k-chunk 0..3 swizzled (shorts)
    const int slot1 = ((quad + 4) ^ lb7) << 3;    // k-chunk 4..7

    __shared__ __align__(16) short sB[12][64][64];   // 96 KB, [kt][hw][k], resident
    __shared__ __align__(16) short sA[2][256][64];   // 64 KB dbuf

    // staging map: 8 lanes per row, row = tid>>3, chunk pre-swizzled by (row&7)
    const int r0      = tid >> 3;                 // 0..63
    const int chsw    = ((tid & 7) ^ (r0 & 7)) << 3;
    const size_t toffA = (size_t)r0 * 768 + chsw;
    const size_t toffB = ((size_t)(b << 10) + hw0 + r0) * 768 + chsw;
    const int ldsoff  = (r0 & ~7) << 6;           // wave-uniform per 8-row group

    short* st0 = &sA[0][0][0] + ldsoff;
    short* st1 = &sA[1][0][0] + ldsoff;
    const short* ArA = &sA[0][0][0] + ((wm + l15) << 6);
    const short* BrA = &sB[0][0][0] + ((wn + l15) << 6);

    f32x4 acc[4][2];
    #pragma unroll
    for (int i = 0; i < 4; ++i) { acc[i][0] = (f32x4){0.f,0.f,0.f,0.f};
                                  acc[i][1] = (f32x4){0.f,0.f,0.f,0.f}; }

    // prologue: B-res (12 calls, once) + A tile (0,0) into buf0
    #pragma unroll
    for (int kt = 0; kt < 12; ++kt)
        load16_lds(Xnt + toffB + kt * 64, &sB[kt][0][0] + ldsoff);
    #pragma unroll
    for (int j = 0; j < 4; ++j)
        load16_lds(Wst + toffA + (size_t)j * 49152, st0 + (j << 12));

    float* wsAb = wsA + (size_t)b * (C_ * 3);

    // ct = 0 (kt0 guards the 16 prologue loads)
    ct_body<true >(ArA, BrA, st0, st1, Wst + toffA,            slot0, slot1, acc);
    dump_acc(acc, wsAb, 0, wm, quad, l15);
    #pragma unroll 1
    for (int ct = 1; ct < 5; ++ct) {
        ct_body<false>(ArA, BrA, st0, st1, Wst + toffA + (size_t)ct * 196608,
                       slot0, slot1, acc);
        dump_acc(acc, wsAb, ct, wm, quad, l15);
    }
    // ct = 5: last phase re-stages tile (5,10) (dead, parity-safe)
    {
        const unsigned short* Acur = Wst + toffA + (size_t)5 * 196608;
        phase< 0, false>(ArA, BrA, st0, st1, Acur +  1 * 64, slot0, slot1, acc);
        phase< 1, true >(ArA, BrA, st0, st1, Acur +  2 * 64, slot0, slot1, acc);
        phase< 2, true >(ArA, BrA, st0, st1, Acur +  3 * 64, slot0, slot1, acc);
        phase< 3, true >(ArA, BrA, st0, st1, Acur +  4 * 64, slot0, slot1, acc);
        phase< 4, true >(ArA, BrA, st0, st1, Acur +  5 * 64, slot0, slot1, acc);
        phase< 5, true >(ArA, BrA, st0, st1, Acur +  6 * 64, slot0, slot1, acc);
        phase< 6, true >(ArA, BrA, st0, st1, Acur +  7 * 64, slot0, slot1, acc);
        phase< 7, true >(ArA, BrA, st0, st1, Acur +  8 * 64, slot0, slot1, acc);
        phase< 8, true >(ArA, BrA, st0, st1, Acur +  9 * 64, slot0, slot1, acc);
        phase< 9, true >(ArA, BrA, st0, st1, Acur + 10 * 64, slot0, slot1, acc);
        phase<10, true >(ArA, BrA, st0, st1, Acur + 11 * 64, slot0, slot1, acc);
        phase<11, true >(ArA, BrA, st0, st1, Acur + 10 * 64, slot0, slot1, acc);
        dump_acc(acc, wsAb, 5, wm, quad, l15);
    }
}

// ---------------------------------------------------------------------------
// K5: out = X * gate. 8 (b,c) rows per block (32 KB/block). (unchanged)
// ---------------------------------------------------------------------------
__global__ __launch_bounds__(256) void final_kernel(const float* __restrict__ X,
                                                    const float* __restrict__ wsA,
                                                    float* __restrict__ out) {
    const int bc0 = blockIdx.x * 8;
    const int tid = threadIdx.x;
    #pragma unroll
    for (int j = 0; j < 8; ++j) {
        const int bc = bc0 + j;
        const float* a = wsA + (size_t)bc * 3;
        const float pd = a[0], pk = a[1], pv = a[2];
        const float g = 0.5f * (pd / ((sqrtf(pk) + EPS_COS) * (sqrtf(pv) + EPS_COS))) + 0.5f;
        const size_t i4 = (size_t)bc * 256 + tid;
        float4 x = reinterpret_cast<const float4*>(X)[i4];
        float4 o;
        o.x = x.x * g; o.y = x.y * g; o.z = x.z * g; o.w = x.w * g;
        reinterpret_cast<float4*>(out)[i4] = o;
    }
}

// ---------------------------------------------------------------------------
extern "C" void kernel_launch(void* const* d_in, const int* in_sizes, int n_in,
                              void* d_out, int out_size, void* d_ws, size_t ws_size,
                              hipStream_t stream) {
    const float* X = (const float*)d_in[0];   // [32,768,32,32]
    const float* W = (const float*)d_in[1];   // [2304,768]
    float* out = (float*)d_out;

    // workspace layout (bytes):
    //   [0,       294912)   wsA   float[32*768*3]  (dot, nk2, nv2)
    //   [425984,  2785280)  Wst   bf16[1536*768]   (interleaved K/V rows)
    //   [2785280, 53116928) Xnt   bf16[32][1024][768]
    char* ws = (char*)d_ws;
    float* wsA           = (float*)ws;
    unsigned short* Wst  = (unsigned short*)(ws + 425984);
    unsigned short* Xnt  = (unsigned short*)(ws + 2785280);

    wconv_kernel<<<dim3(1536),   192, 0, stream>>>(W, Wst, wsA);
    norm_kernel <<<dim3(16, 32), 256, 0, stream>>>(X, Xnt);
    gemm_kernel <<<dim3(16, 32), 512, 0, stream>>>(Wst, Xnt, wsA);
    final_kernel<<<dim3(3072),   256, 0, stream>>>(X, wsA, out);
}